// Round 1
// baseline (1211.554 us; speedup 1.0000x reference)
//
#include <hip/hip_runtime.h>
#include <cstddef>

// ConvLSTM cell, fp32 direct conv + fused BN-stat collection.
// Pipeline: wtrans ×8 -> conv_e1 -> red -> conv_e2 -> red -> conv_gates(z=4) -> red
//           -> lstm_elem -> conv_r1 -> red -> conv_r2(pad4) -> red -> holes gather.

typedef float f4 __attribute__((ext_vector_type(4)));

#define H_   512
#define W_   512
#define HW_  (H_ * W_)
#define EPS_ 1e-5f
#define RMH  518
#define RMHW (RMH * RMH)
#define TS   16

static __device__ __forceinline__ float sigmoidf_(float x) { return 1.f / (1.f + expf(-x)); }

// ---- weight transpose: [COUT][CIN][3][3] -> [CIN*9][COUT] (co contiguous for s_load) ----
__global__ void wtrans_kernel(const float* __restrict__ src, float* __restrict__ dst,
                              int cin, int cout) {
    int n = cout * cin * 9;
    int idx = blockIdx.x * 256 + threadIdx.x;
    if (idx < n) {
        int co = idx / (cin * 9);
        int r  = idx - co * cin * 9;   // ci*9 + k
        dst[r * cout + co] = src[idx];
    }
}

// ---- direct 3x3 conv, 16x16 tile, COUT accumulators/thread ----
// MODE: 0 = raw input; 1 = normalize input (BN); 2 = normalize + relu;
//       3 = concat: ch<32 from in2 raw (prev_h), ch>=32 from in normalized (x_emb).
// Writes raw conv output + per-block per-channel (sum, sumsq) partials.
template <int CIN, int COUT, int PAD, int MODE>
__global__ __launch_bounds__(256) void conv3x3_kernel(
    const float* __restrict__ in, const float* __restrict__ sums,
    const float* __restrict__ in2, const float* __restrict__ wt,
    float* __restrict__ out, float* __restrict__ partials,
    int OH, int OW, int IH, int IW, float inv_n_in)
{
    constexpr int CH  = (CIN < 8) ? CIN : 8;      // input-channel chunk in LDS
    constexpr int NC  = (MODE == 3) ? 32 : CIN;   // channels needing normalization
    constexpr int NCA = (MODE >= 1) ? NC : 1;

    __shared__ float smem[CH * 18 * 18];
    __shared__ float s_mean[NCA], s_istd[NCA];
    __shared__ float red[4][COUT][2];

    const int tid = threadIdx.x;
    const int tx = tid & 15, ty = tid >> 4;
    const int bx = blockIdx.x, by = blockIdx.y, z = blockIdx.z;
    const int IHW = IH * IW;

    if constexpr (MODE >= 1) {
        if (tid < NC) {
            float s = sums[tid * 2], ss = sums[tid * 2 + 1];
            float m = s * inv_n_in;
            s_mean[tid] = m;
            s_istd[tid] = rsqrtf(ss * inv_n_in - m * m + EPS_);
        }
    }

    float acc[COUT];
#pragma unroll
    for (int i = 0; i < COUT; ++i) acc[i] = 0.f;

    const float* wz = wt + (size_t)z * CIN * 9 * COUT;

    for (int cc = 0; cc < CIN / CH; ++cc) {
        __syncthreads();   // also covers s_mean readiness on first iter
        for (int i = tid; i < CH * 324; i += 256) {
            int ci = i / 324;
            int rem = i - ci * 324;
            int ly = rem / 18, lx = rem - ly * 18;
            int c = cc * CH + ci;
            int gy = by * TS + ly - PAD, gx = bx * TS + lx - PAD;
            float v = 0.f;
            if ((unsigned)gy < (unsigned)IH && (unsigned)gx < (unsigned)IW) {
                if (MODE == 3 && c < 32) {
                    v = in2[(size_t)c * IHW + gy * IW + gx];
                } else {
                    int cs = (MODE == 3) ? c - 32 : c;
                    v = in[(size_t)cs * IHW + gy * IW + gx];
                    if constexpr (MODE >= 1) {
                        v = (v - s_mean[cs]) * s_istd[cs];
                        if constexpr (MODE == 2) v = fmaxf(v, 0.f);
                    }
                }
            }
            smem[i] = v;
        }
        __syncthreads();

        const float* wc = wz + (size_t)cc * CH * 9 * COUT;
#pragma unroll
        for (int ci = 0; ci < CH; ++ci) {
#pragma unroll
            for (int kk = 0; kk < 9; ++kk) {
                const int ky = kk / 3, kx = kk - ky * 3;
                float v = smem[ci * 324 + (ty + ky) * 18 + (tx + kx)];
                const float* w = wc + (ci * 9 + kk) * COUT;
#pragma unroll
                for (int co = 0; co < COUT; ++co)
                    acc[co] = fmaf(v, w[co], acc[co]);
            }
        }
    }

    const int oy = by * TS + ty, ox = bx * TS + tx;
    const bool valid = (oy < OH) && (ox < OW);
    float* oz = out + (size_t)z * COUT * OH * OW;
    if (valid) {
#pragma unroll
        for (int co = 0; co < COUT; ++co)
            oz[(size_t)co * OH * OW + oy * OW + ox] = acc[co];
    }

    // per-block BN partial sums
    const float scale = valid ? 1.f : 0.f;
    const int wave = tid >> 6, lane = tid & 63;
#pragma unroll
    for (int co = 0; co < COUT; ++co) {
        float s = acc[co] * scale;
        float ss = acc[co] * acc[co] * scale;
#pragma unroll
        for (int o = 32; o > 0; o >>= 1) {
            s += __shfl_down(s, o);
            ss += __shfl_down(ss, o);
        }
        if (lane == 0) { red[wave][co][0] = s; red[wave][co][1] = ss; }
    }
    __syncthreads();
    if (tid < COUT) {
        float s = red[0][tid][0] + red[1][tid][0] + red[2][tid][0] + red[3][tid][0];
        float ss = red[0][tid][1] + red[1][tid][1] + red[2][tid][1] + red[3][tid][1];
        int nbxy = gridDim.x * gridDim.y;
        int bl = z * nbxy + by * gridDim.x + bx;
        partials[((size_t)bl * COUT + tid) * 2]     = s;
        partials[((size_t)bl * COUT + tid) * 2 + 1] = ss;
    }
}

// ---- reduce per-block partials -> per-channel (sum, sumsq) ----
// partials layout: [gate][nb][cout][2]; grid.x = total channels (gates*cout)
__global__ __launch_bounds__(256) void reduce_kernel(const float* __restrict__ p,
                                                     float* __restrict__ sums,
                                                     int nb, int cout) {
    int c = blockIdx.x;
    int g = c / cout, co = c - g * cout;
    const float* base = p + (size_t)g * nb * cout * 2;
    float s = 0.f, ss = 0.f;
    for (int i = threadIdx.x; i < nb; i += 256) {
        s  += base[((size_t)i * cout + co) * 2];
        ss += base[((size_t)i * cout + co) * 2 + 1];
    }
#pragma unroll
    for (int o = 32; o > 0; o >>= 1) {
        s += __shfl_down(s, o);
        ss += __shfl_down(ss, o);
    }
    __shared__ float ls[4], lss[4];
    int w = threadIdx.x >> 6;
    if ((threadIdx.x & 63) == 0) { ls[w] = s; lss[w] = ss; }
    __syncthreads();
    if (threadIdx.x == 0) {
        float S = ls[0] + ls[1] + ls[2] + ls[3];
        float SS = lss[0] + lss[1] + lss[2] + lss[3];
        sums[c * 2] = S;
        sums[c * 2 + 1] = SS;
    }
}

// ---- LSTM elementwise: normalize gates, sigmoid/tanh, next_c/next_h ----
__global__ __launch_bounds__(256) void lstm_elem_kernel(
    const float* __restrict__ gates, const float* __restrict__ S,
    const float* __restrict__ prev_c, float* __restrict__ out)
{
    __shared__ float mn[128], is_[128];
    int tid = threadIdx.x;
    if (tid < 128) {
        float s = S[tid * 2], ss = S[tid * 2 + 1];
        float m = s * (1.f / HW_);
        mn[tid] = m;
        is_[tid] = rsqrtf(ss * (1.f / HW_) - m * m + EPS_);
    }
    __syncthreads();
    size_t p = (size_t)(blockIdx.x * 256 + tid) * 4;
    for (int ch = 0; ch < 32; ++ch) {
        f4 fv = *(const f4*)(gates + (size_t)ch * HW_ + p);
        f4 iv = *(const f4*)(gates + (size_t)(32 + ch) * HW_ + p);
        f4 cv = *(const f4*)(gates + (size_t)(64 + ch) * HW_ + p);
        f4 ov = *(const f4*)(gates + (size_t)(96 + ch) * HW_ + p);
        f4 pc = *(const f4*)(prev_c + (size_t)ch * HW_ + p);
        float fm = mn[ch], fs = is_[ch];
        float im = mn[32 + ch], isd = is_[32 + ch];
        float cm = mn[64 + ch], cs = is_[64 + ch];
        float om = mn[96 + ch], os = is_[96 + ch];
        f4 nc, nh;
#pragma unroll
        for (int k = 0; k < 4; ++k) {
            float f = sigmoidf_((fv[k] - fm) * fs);
            float i = sigmoidf_((iv[k] - im) * isd);
            float c = tanhf((cv[k] - cm) * cs);
            float o = sigmoidf_((ov[k] - om) * os);
            float ncv = pc[k] * f + i * c;
            nc[k] = ncv;
            nh[k] = tanhf(ncv) * o;
        }
        *(f4*)(out + (size_t)ch * HW_ + p) = nc;
        *(f4*)(out + (size_t)32 * HW_ + (size_t)ch * HW_ + p) = nh;
    }
}

// ---- hole gather: normalize rm at (hx+3, hy+3), 1x1 "matmul" + bias ----
__global__ void holes_kernel(const float* __restrict__ rm, const float* __restrict__ S,
                             const int* __restrict__ holes,
                             const float* __restrict__ w_oil, const float* __restrict__ b_oil,
                             const float* __restrict__ w_wat, const float* __restrict__ b_wat,
                             const float* __restrict__ w_gas, const float* __restrict__ b_gas,
                             float* __restrict__ res)
{
    int i = threadIdx.x;  // 256 holes, 1 block
    int hx = holes[i * 2], hy = holes[i * 2 + 1];
    const float invn = 1.f / (float)RMHW;
#pragma unroll
    for (int c = 0; c < 3; ++c) {
        float s = S[c * 2], ss = S[c * 2 + 1];
        float m = s * invn;
        float istd = rsqrtf(ss * invn - m * m + EPS_);
        float raw = rm[(size_t)c * RMHW + (size_t)(hx + 3) * RMH + (hy + 3)];
        float nv = (raw - m) * istd;
        float w = (c == 0) ? w_oil[0] : (c == 1) ? w_wat[0] : w_gas[0];
        float b = (c == 0) ? b_oil[0] : (c == 1) ? b_wat[0] : b_gas[0];
        res[i * 3 + c] = nv * w + b;
    }
}

extern "C" void kernel_launch(void* const* d_in, const int* in_sizes, int n_in,
                              void* d_out, int out_size, void* d_ws, size_t ws_size,
                              hipStream_t stream) {
    const float* x      = (const float*)d_in[0];
    const float* prev_c = (const float*)d_in[1];
    const float* prev_h = (const float*)d_in[2];
    const int*   holes  = (const int*)d_in[3];
    const float* w_e1 = (const float*)d_in[4];
    const float* w_e2 = (const float*)d_in[5];
    const float* w_f  = (const float*)d_in[6];
    const float* w_i  = (const float*)d_in[7];
    const float* w_c  = (const float*)d_in[8];
    const float* w_o  = (const float*)d_in[9];
    const float* w_r1 = (const float*)d_in[10];
    const float* w_r2 = (const float*)d_in[11];
    const float* w_oil = (const float*)d_in[12];
    const float* b_oil = (const float*)d_in[13];
    const float* w_wat = (const float*)d_in[14];
    const float* b_wat = (const float*)d_in[15];
    const float* w_gas = (const float*)d_in[16];
    const float* b_gas = (const float*)d_in[17];

    float* out = (float*)d_out;
    float* ws  = (float*)d_ws;

    // workspace layout (floats); y1 region reused for r1, y2 region reused for rm
    size_t o = 0;
    float* wt_e1 = ws + o; o += 4 * 9 * 32;        // 1152
    float* wt_e2 = ws + o; o += 32 * 9 * 32;       // 9216
    float* wt_g  = ws + o; o += 4 * 64 * 9 * 32;   // 73728
    float* wt_r1 = ws + o; o += 32 * 9 * 32;       // 9216
    float* wt_r2 = ws + o; o += 32 * 9 * 3;        // 864
    float* y1    = ws + o; o += (size_t)32 * HW_;  // 8.4M (reused as r1)
    float* y2    = ws + o; o += (size_t)32 * HW_;  // 8.4M (reused as rm)
    float* gates = ws + o; o += (size_t)128 * HW_; // 33.6M
    float* P1 = ws + o; o += 1024 * 32 * 2;
    float* P2 = ws + o; o += 1024 * 32 * 2;
    float* P3 = ws + o; o += 4096 * 32 * 2;
    float* P4 = ws + o; o += 1024 * 32 * 2;
    float* P5 = ws + o; o += 1089 * 3 * 2;
    float* S1 = ws + o; o += 64;
    float* S2 = ws + o; o += 64;
    float* S3 = ws + o; o += 256;
    float* S4 = ws + o; o += 64;
    float* S5 = ws + o; o += 8;
    float* r1 = y1;  // y1 dead after conv_e2
    float* rm = y2;  // y2 dead after gate conv

    const float invHW = 1.f / (float)HW_;
    dim3 blk(256);

    // weight transposes
    wtrans_kernel<<<dim3(5), blk, 0, stream>>>(w_e1, wt_e1, 4, 32);
    wtrans_kernel<<<dim3(36), blk, 0, stream>>>(w_e2, wt_e2, 32, 32);
    wtrans_kernel<<<dim3(72), blk, 0, stream>>>(w_f, wt_g + 0 * 64 * 9 * 32, 64, 32);
    wtrans_kernel<<<dim3(72), blk, 0, stream>>>(w_i, wt_g + 1 * 64 * 9 * 32, 64, 32);
    wtrans_kernel<<<dim3(72), blk, 0, stream>>>(w_c, wt_g + 2 * 64 * 9 * 32, 64, 32);
    wtrans_kernel<<<dim3(72), blk, 0, stream>>>(w_o, wt_g + 3 * 64 * 9 * 32, 64, 32);
    wtrans_kernel<<<dim3(36), blk, 0, stream>>>(w_r1, wt_r1, 32, 32);
    wtrans_kernel<<<dim3(4),  blk, 0, stream>>>(w_r2, wt_r2, 32, 3);

    // conv_e1: x(4ch) -> y1 raw + P1
    conv3x3_kernel<4, 32, 1, 0><<<dim3(32, 32, 1), blk, 0, stream>>>(
        x, nullptr, nullptr, wt_e1, y1, P1, H_, W_, H_, W_, invHW);
    reduce_kernel<<<dim3(32), blk, 0, stream>>>(P1, S1, 1024, 32);

    // conv_e2: norm+relu(y1) -> y2 raw + P2
    conv3x3_kernel<32, 32, 1, 2><<<dim3(32, 32, 1), blk, 0, stream>>>(
        y1, S1, nullptr, wt_e2, y2, P2, H_, W_, H_, W_, invHW);
    reduce_kernel<<<dim3(32), blk, 0, stream>>>(P2, S2, 1024, 32);

    // gate convs: concat[prev_h raw, norm(y2)] -> gates raw + P3 (z = f,i,c,o)
    conv3x3_kernel<64, 32, 1, 3><<<dim3(32, 32, 4), blk, 0, stream>>>(
        y2, S2, prev_h, wt_g, gates, P3, H_, W_, H_, W_, invHW);
    reduce_kernel<<<dim3(128), blk, 0, stream>>>(P3, S3, 1024, 32);

    // LSTM elementwise -> d_out[next_c, next_h]
    lstm_elem_kernel<<<dim3(256), blk, 0, stream>>>(gates, S3, prev_c, out);

    // conv_r1: next_h raw -> r1 raw + P4
    conv3x3_kernel<32, 32, 1, 0><<<dim3(32, 32, 1), blk, 0, stream>>>(
        out + (size_t)32 * HW_, nullptr, nullptr, wt_r1, r1, P4, H_, W_, H_, W_, invHW);
    reduce_kernel<<<dim3(32), blk, 0, stream>>>(P4, S4, 1024, 32);

    // conv_r2: norm+relu(r1), pad=4 -> rm raw (3 x 518 x 518) + P5
    conv3x3_kernel<32, 3, 4, 2><<<dim3(33, 33, 1), blk, 0, stream>>>(
        r1, S4, nullptr, wt_r2, rm, P5, RMH, RMH, H_, W_, invHW);
    reduce_kernel<<<dim3(3), blk, 0, stream>>>(P5, S5, 1089, 3);

    // hole gather -> d_out[res]
    holes_kernel<<<dim3(1), blk, 0, stream>>>(
        rm, S5, holes, w_oil, b_oil, w_wat, b_wat, w_gas, b_gas,
        out + (size_t)64 * HW_);
}